// Round 3
// baseline (133.777 us; speedup 1.0000x reference)
//
#include <hip/hip_runtime.h>
#include <hip/hip_bf16.h>

// EmbeddingLoss: loss = sum_{i<j} [ same ? mse : max(0,1-mse) ] / (B*(B-1))
// mse_ij = (sq_i + sq_j - 2*gram_ij)/D, gram = E E^T.
// Round 3: NO LDS. Eb (4MB bf16) is L2-resident; MFMA fragments for a
// row-major N x K operand are 16B-contiguous row segments -> load bf16x8
// straight from global. Zero barriers in main loop; TLP hides L2 latency.
// Wave = 64x128 (4x8 frags), block = 2x2 waves = 128x256, upper-tri blocks.

#define BN 8192
#define DK 256

typedef __bf16 bf16x8 __attribute__((ext_vector_type(8)));
typedef float f32x4 __attribute__((ext_vector_type(4)));

static __device__ __forceinline__ unsigned short f2bf(float f) {
    unsigned u = __builtin_bit_cast(unsigned, f);
    u += 0x7fffu + ((u >> 16) & 1u);          // round-to-nearest-even
    return (unsigned short)(u >> 16);
}

// ---------------- prep: fp32->bf16 (ws) + fp32 row norms (ws), zero out ----
__global__ __launch_bounds__(256) void embl_prep(
    const float* __restrict__ E, unsigned short* __restrict__ Eb,
    float* __restrict__ sq, float* __restrict__ out)
{
    const int lane = threadIdx.x & 63;
    const int wid  = threadIdx.x >> 6;
    const int row  = blockIdx.x * 4 + wid;    // one row per wave
    if (blockIdx.x == 0 && threadIdx.x == 0) *out = 0.0f;
    const float4 v = *(const float4*)(E + row * DK + lane * 4);
    float s = v.x*v.x + v.y*v.y + v.z*v.z + v.w*v.w;
    ushort4 o;
    o.x = f2bf(v.x); o.y = f2bf(v.y); o.z = f2bf(v.z); o.w = f2bf(v.w);
    *(ushort4*)(Eb + row * DK + lane * 4) = o;
    #pragma unroll
    for (int off = 32; off > 0; off >>= 1) s += __shfl_xor(s, off, 64);
    if (lane == 0) sq[row] = s;
}

// ---------------- main: register-only gram tile + hinge epilogue -----------
// grid: for tj in 0..31 (256-col tiles), ti in 0..2*tj+1 (128-row tiles)
// => 1056 blocks; strict-upper mask applied per element.
__global__ __launch_bounds__(256, 2) void embl_gram(
    const unsigned short* __restrict__ Ebu, const float* __restrict__ sq,
    const int* __restrict__ lab, float* __restrict__ out)
{
    __shared__ float wpart[4];

    // XCD-aware chunked swizzle: 1056 = 8 * 132 (bijective)
    const int bid = (blockIdx.x & 7) * 132 + (blockIdx.x >> 3);

    // decode bid -> (tj, ti): cumulative blocks before tj = tj^2 + tj
    int tj = (int)((sqrtf((float)(4 * bid + 1)) - 1.0f) * 0.5f);
    while (tj * tj + tj > bid) --tj;
    while ((tj + 1) * (tj + 1) + (tj + 1) <= bid) ++tj;
    const int ti = bid - tj * tj - tj;

    const int tid  = threadIdx.x;
    const int lane = tid & 63;
    const int wid  = tid >> 6;
    const int wr   = wid >> 1;          // wave row (0..1) -> 64-row offset
    const int wc   = wid & 1;           // wave col (0..1) -> 128-col offset

    const int gi0 = ti * 128 + wr * 64;
    const int gj0 = tj * 256 + wc * 128;

    // per-lane fragment base addresses (row-major bf16, 512 B/row)
    const char* Ebc = (const char*)Ebu;
    const char* pa = Ebc + ((long)(gi0 + (lane & 15))) * 512 + (lane >> 4) * 16;
    const char* pb = Ebc + ((long)(gj0 + (lane & 15))) * 512 + (lane >> 4) * 16;

    f32x4 acc[4][8] = {};
    bf16x8 a0[4], b0[8], a1[4], b1[8];

    #pragma unroll
    for (int m = 0; m < 4; ++m) a0[m] = *(const bf16x8*)(pa + m * 8192);
    #pragma unroll
    for (int n = 0; n < 8; ++n) b0[n] = *(const bf16x8*)(pb + n * 8192);

    #pragma unroll
    for (int kp = 0; kp < 4; ++kp) {
        // prefetch odd k-step
        #pragma unroll
        for (int m = 0; m < 4; ++m)
            a1[m] = *(const bf16x8*)(pa + (2 * kp + 1) * 64 + m * 8192);
        #pragma unroll
        for (int n = 0; n < 8; ++n)
            b1[n] = *(const bf16x8*)(pb + (2 * kp + 1) * 64 + n * 8192);
        // compute even k-step
        #pragma unroll
        for (int m = 0; m < 4; ++m)
            #pragma unroll
            for (int n = 0; n < 8; ++n)
                acc[m][n] = __builtin_amdgcn_mfma_f32_16x16x32_bf16(
                    a0[m], b0[n], acc[m][n], 0, 0, 0);
        // prefetch next even k-step
        if (kp < 3) {
            #pragma unroll
            for (int m = 0; m < 4; ++m)
                a0[m] = *(const bf16x8*)(pa + (2 * kp + 2) * 64 + m * 8192);
            #pragma unroll
            for (int n = 0; n < 8; ++n)
                b0[n] = *(const bf16x8*)(pb + (2 * kp + 2) * 64 + n * 8192);
        }
        // compute odd k-step
        #pragma unroll
        for (int m = 0; m < 4; ++m)
            #pragma unroll
            for (int n = 0; n < 8; ++n)
                acc[m][n] = __builtin_amdgcn_mfma_f32_16x16x32_bf16(
                    a1[m], b1[n], acc[m][n], 0, 0, 0);
    }

    // epilogue: C/D layout col=lane&15, row=(lane>>4)*4+reg  [m89-verified]
    float lsum = 0.0f;
    #pragma unroll
    for (int m = 0; m < 4; ++m) {
        const int ibase = gi0 + m * 16 + (lane >> 4) * 4;
        float sqi[4]; int li[4];
        #pragma unroll
        for (int r = 0; r < 4; ++r) { sqi[r] = sq[ibase + r]; li[r] = lab[ibase + r]; }
        #pragma unroll
        for (int n = 0; n < 8; ++n) {
            const int j = gj0 + n * 16 + (lane & 15);
            const float sqj = sq[j];
            const int   lj  = lab[j];
            #pragma unroll
            for (int r = 0; r < 4; ++r) {
                const int i = ibase + r;
                const float mse = (sqi[r] + sqj - 2.0f * acc[m][n][r]) * (1.0f / 256.0f);
                float v = (li[r] == lj) ? mse : fmaxf(0.0f, 1.0f - mse);
                if (i >= j) v = 0.0f;          // strict upper triangle
                lsum += v;
            }
        }
    }

    #pragma unroll
    for (int off = 32; off > 0; off >>= 1) lsum += __shfl_xor(lsum, off, 64);
    if (lane == 0) wpart[wid] = lsum;
    __syncthreads();
    if (tid == 0) {
        const float scale = 1.0f / ((float)BN * (float)(BN - 1));
        atomicAdd(out, (wpart[0] + wpart[1] + wpart[2] + wpart[3]) * scale);
    }
}

extern "C" void kernel_launch(void* const* d_in, const int* in_sizes, int n_in,
                              void* d_out, int out_size, void* d_ws, size_t ws_size,
                              hipStream_t stream) {
    const float* E   = (const float*)d_in[0];
    const int*   lab = (const int*)d_in[1];
    float*       out = (float*)d_out;

    unsigned short* Eb = (unsigned short*)d_ws;                       // 4 MiB
    float*          sq = (float*)((char*)d_ws + (size_t)BN * DK * 2); // 32 KiB

    embl_prep<<<BN / 4, 256, 0, stream>>>(E, Eb, sq, out);
    embl_gram<<<1056, 256, 0, stream>>>(Eb, sq, lab, out);
}

// Round 4
// 101.539 us; speedup vs baseline: 1.3175x; 1.3175x over previous
//
#include <hip/hip_runtime.h>
#include <hip/hip_bf16.h>

// EmbeddingLoss: loss = sum_{i<j} [ same ? mse : max(0,1-mse) ] / (B*(B-1))
// mse_ij = (sq_i + sq_j - 2*gram_ij)/D, gram = E E^T.
// Round 4: back to the proven global_load_lds staging structure, upgraded:
// 32x32x16 MFMA, dbuf LDS (64KB -> 2 blocks/CU), raw s_barrier + counted
// vmcnt(8) pipeline fully unrolled over the 4 K-tiles, T2 XOR swizzle
// (linear LDS dest + inverse-swizzled source + swizzled ds_read).

#define BN 8192
#define DK 256
#define NT 64                      // BN/128 tiles per dim
#define NBLK (NT * (NT + 1) / 2)   // 2080 upper-tri tiles = 8*260

typedef __bf16 bf16x8 __attribute__((ext_vector_type(8)));
typedef float f32x16 __attribute__((ext_vector_type(16)));

typedef const __attribute__((address_space(1))) void* gas_vp;
typedef __attribute__((address_space(3))) void* las_vp;

static __device__ __forceinline__ unsigned short f2bf(float f) {
    unsigned u = __builtin_bit_cast(unsigned, f);
    u += 0x7fffu + ((u >> 16) & 1u);          // round-to-nearest-even
    return (unsigned short)(u >> 16);
}

// ---------------- prep: fp32->bf16 (ws) + fp32 row norms (ws), zero out ----
__global__ __launch_bounds__(256) void embl_prep(
    const float* __restrict__ E, unsigned short* __restrict__ Eb,
    float* __restrict__ sq, float* __restrict__ out)
{
    const int lane = threadIdx.x & 63;
    const int wid  = threadIdx.x >> 6;
    const int row  = blockIdx.x * 4 + wid;    // one row per wave
    if (blockIdx.x == 0 && threadIdx.x == 0) *out = 0.0f;
    const float4 v = *(const float4*)(E + row * DK + lane * 4);
    float s = v.x*v.x + v.y*v.y + v.z*v.z + v.w*v.w;
    ushort4 o;
    o.x = f2bf(v.x); o.y = f2bf(v.y); o.z = f2bf(v.z); o.w = f2bf(v.w);
    *(ushort4*)(Eb + row * DK + lane * 4) = o;
    #pragma unroll
    for (int off = 32; off > 0; off >>= 1) s += __shfl_xor(s, off, 64);
    if (lane == 0) sq[row] = s;
}

// ---------------- main: 128x128 gram tile, 4 waves, dbuf pipeline ----------
__global__ __launch_bounds__(256, 2) void embl_gram(
    const unsigned short* __restrict__ Ebu, const float* __restrict__ sq,
    const int* __restrict__ lab, float* __restrict__ out)
{
    __shared__ alignas(16) __bf16 As[2][128 * 64];
    __shared__ alignas(16) __bf16 Bs[2][128 * 64];
    __shared__ float wpart[4];

    // XCD-aware chunked swizzle, bijective: 2080 = 8 * 260
    const int bid = (blockIdx.x & 7) * 260 + (blockIdx.x >> 3);
    // upper-tri decode: bid -> (ti, tj), ti <= tj
    int t = bid, ti = 0, rl = NT;
    while (t >= rl) { t -= rl; --rl; ++ti; }
    const int tj = ti + t;

    const int tid  = threadIdx.x;
    const int lane = tid & 63;
    const int wid  = tid >> 6;
    const int wr   = wid >> 1;          // 0..1 -> 64-row half
    const int wc   = wid & 1;           // 0..1 -> 64-col half

    const int lrow = lane & 31;         // MFMA row-in-frag
    const int lhi  = lane >> 5;         // k-half select
    const int lx   = lane & 7;          // read-side XOR key (== row & 7)

    const char* Ebc = (const char*)Ebu;
    const int arow = ti * 128;
    const int brow = tj * 128;

    // stage one operand K-tile (128 rows x 64 cols bf16 = 16KB): 4 loads/thr.
    // Linear LDS dest chunk c; global source chunk XOR-swizzled (involution).
#define STAGE(dst, grow, kt)                                                   \
    {                                                                          \
        _Pragma("unroll")                                                      \
        for (int it_ = 0; it_ < 4; ++it_) {                                    \
            const int c_   = it_ * 256 + tid;                                  \
            const int row_ = c_ >> 3;                                          \
            const int sch_ = (c_ & 7) ^ (row_ & 7);                            \
            __builtin_amdgcn_global_load_lds(                                  \
                (gas_vp)(Ebc + (long)((grow) + row_) * 512 + (kt) * 128 + sch_ * 16), \
                (las_vp)((char*)(dst) + c_ * 16), 16, 0, 0);                   \
        }                                                                      \
    }

    // vmcnt-counted tile boundary: wait-N, then raw barrier (no full drain)
#define WAITVM(N)                                                              \
    {                                                                          \
        asm volatile("s_waitcnt vmcnt(" #N ")" ::: "memory");                  \
        __builtin_amdgcn_sched_barrier(0);                                     \
        __builtin_amdgcn_s_barrier();                                          \
        __builtin_amdgcn_sched_barrier(0);                                     \
    }

    // swizzled fragment reads (rows stride 128B; chunk ^= row&7 == lane&7)
#define LDA(buf, m, kc)                                                        \
    (*(const bf16x8*)((const char*)&As[buf][0] +                               \
        (wr * 64 + (m) * 32 + lrow) * 128 + ((((kc) * 2) + lhi) ^ lx) * 16))
#define LDB(buf, n, kc)                                                        \
    (*(const bf16x8*)((const char*)&Bs[buf][0] +                               \
        (wc * 64 + (n) * 32 + lrow) * 128 + ((((kc) * 2) + lhi) ^ lx) * 16))

#define MFMA32(a, b, c) __builtin_amdgcn_mfma_f32_32x32x16_bf16(a, b, c, 0, 0, 0)

#define TILE(buf)                                                              \
    {                                                                          \
        bf16x8 a_[2][4], b_[2][4];                                             \
        _Pragma("unroll")                                                      \
        for (int kc = 0; kc < 4; ++kc) {                                       \
            a_[0][kc] = LDA(buf, 0, kc);                                       \
            a_[1][kc] = LDA(buf, 1, kc);                                       \
            b_[0][kc] = LDB(buf, 0, kc);                                       \
            b_[1][kc] = LDB(buf, 1, kc);                                       \
        }                                                                      \
        __builtin_amdgcn_s_setprio(1);                                         \
        _Pragma("unroll")                                                      \
        for (int kc = 0; kc < 4; ++kc) {                                       \
            acc[0][0] = MFMA32(a_[0][kc], b_[0][kc], acc[0][0]);               \
            acc[0][1] = MFMA32(a_[0][kc], b_[1][kc], acc[0][1]);               \
            acc[1][0] = MFMA32(a_[1][kc], b_[0][kc], acc[1][0]);               \
            acc[1][1] = MFMA32(a_[1][kc], b_[1][kc], acc[1][1]);               \
        }                                                                      \
        __builtin_amdgcn_s_setprio(0);                                         \
        __builtin_amdgcn_sched_barrier(0);                                     \
        __builtin_amdgcn_s_barrier();   /* all waves done reading buf */       \
        __builtin_amdgcn_sched_barrier(0);                                     \
    }

    f32x16 acc[2][2] = {};

    // prologue: stage K-tiles 0 and 1 (16 loads outstanding/thread)
    STAGE(As[0], arow, 0); STAGE(Bs[0], brow, 0);
    STAGE(As[1], arow, 1); STAGE(Bs[1], brow, 1);
    WAITVM(8);                          // t0 landed
    TILE(0);
    STAGE(As[0], arow, 2); STAGE(Bs[0], brow, 2);
    WAITVM(8);                          // t1 landed (t2 in flight)
    TILE(1);
    STAGE(As[1], arow, 3); STAGE(Bs[1], brow, 3);
    WAITVM(8);                          // t2 landed (t3 in flight)
    TILE(0);
    WAITVM(0);                          // t3 landed
    TILE(1);

    // ---- epilogue: C/D layout col=lane&31, row=(reg&3)+8*(reg>>2)+4*lhi ----
    const int gi0 = arow + wr * 64;
    const int gj0 = brow + wc * 64;
    float lsum = 0.0f;

#define EPI(MASKED)                                                            \
    {                                                                          \
        float sqjv[2]; int ljv[2], jv[2];                                      \
        _Pragma("unroll")                                                      \
        for (int n_ = 0; n_ < 2; ++n_) {                                       \
            jv[n_] = gj0 + n_ * 32 + lrow;                                     \
            sqjv[n_] = sq[jv[n_]]; ljv[n_] = lab[jv[n_]];                      \
        }                                                                      \
        _Pragma("unroll")                                                      \
        for (int m_ = 0; m_ < 2; ++m_)                                         \
        _Pragma("unroll")                                                      \
        for (int rq = 0; rq < 4; ++rq)                                         \
        _Pragma("unroll")                                                      \
        for (int rr = 0; rr < 4; ++rr) {                                       \
            const int i_ = gi0 + m_ * 32 + 4 * lhi + rq * 8 + rr;              \
            const float sqi_ = sq[i_]; const int li_ = lab[i_];                \
            _Pragma("unroll")                                                  \
            for (int n_ = 0; n_ < 2; ++n_) {                                   \
                const float mse_ =                                             \
                    (sqi_ + sqjv[n_] - 2.0f * acc[m_][n_][rq * 4 + rr]) *      \
                    (1.0f / 256.0f);                                           \
                float v_ = (li_ == ljv[n_]) ? mse_                             \
                                            : fmaxf(0.0f, 1.0f - mse_);       \
                if (MASKED && i_ >= jv[n_]) v_ = 0.0f;                         \
                lsum += v_;                                                    \
            }                                                                  \
        }                                                                      \
    }

    if (ti == tj) { EPI(1) } else { EPI(0) }

    #pragma unroll
    for (int off = 32; off > 0; off >>= 1) lsum += __shfl_xor(lsum, off, 64);
    if (lane == 0) wpart[wid] = lsum;
    __syncthreads();
    if (tid == 0) {
        const float scale = 1.0f / ((float)BN * (float)(BN - 1));
        atomicAdd(out, (wpart[0] + wpart[1] + wpart[2] + wpart[3]) * scale);
    }
}

extern "C" void kernel_launch(void* const* d_in, const int* in_sizes, int n_in,
                              void* d_out, int out_size, void* d_ws, size_t ws_size,
                              hipStream_t stream) {
    const float* E   = (const float*)d_in[0];
    const int*   lab = (const int*)d_in[1];
    float*       out = (float*)d_out;

    unsigned short* Eb = (unsigned short*)d_ws;                       // 4 MiB
    float*          sq = (float*)((char*)d_ws + (size_t)BN * DK * 2); // 32 KiB

    embl_prep<<<BN / 4, 256, 0, stream>>>(E, Eb, sq, out);
    embl_gram<<<NBLK, 256, 0, stream>>>(Eb, sq, lab, out);
}